// Round 1
// baseline (12242.332 us; speedup 1.0000x reference)
//
#include <hip/hip_runtime.h>
#include <cmath>

#define T_STEPS 8
#define NN 50000
#define EE 800000

__device__ __forceinline__ float sigf(float x){ return 1.f/(1.f + __expf(-x)); }
__device__ __forceinline__ float tanhfast(float x){ return 1.f - 2.f/(1.f + __expf(2.f*x)); }

// Build fused weight matrix Wcat[256][256]: rows = [x(64) | Tx0(64) | Tx1(64) | Tx2(64)],
// cols = [gate_i(64) | gate_f(64) | gate_g(64) | gate_o(64)]. Also bcat[256].
__global__ void k_build_w(const float* __restrict__ Wx, const float* __restrict__ Th,
                          const float* __restrict__ b, float* __restrict__ Wcat,
                          float* __restrict__ bcat){
    int idx = blockIdx.x*blockDim.x + threadIdx.x;
    if (idx >= 256*256) return;
    int k = idx >> 8, c = idx & 255;
    int g = c >> 6, cc = c & 63, kb = k >> 6, kk = k & 63;
    float v;
    if (kb == 0) v = Wx[(g*64 + kk)*64 + cc];
    else         v = Th[((g*3 + (kb-1))*64 + kk)*64 + cc];
    Wcat[idx] = v;
    if (idx < 256) bcat[idx] = b[idx];
}

__global__ void k_deg(const int* __restrict__ src, const float* __restrict__ w,
                      float* __restrict__ deg, int E){
    int e = blockIdx.x*blockDim.x + threadIdx.x;
    if (e < E) unsafeAtomicAdd(&deg[src[e]], w[e]);
}

__global__ void k_dinv(const float* __restrict__ deg, float* __restrict__ dinv, int N){
    int n = blockIdx.x*blockDim.x + threadIdx.x;
    if (n < N){
        float d = deg[n];
        dinv[n] = d > 0.f ? rsqrtf(fmaxf(d, 1e-12f)) : 0.f;
    }
}

__global__ void k_norm(const int* __restrict__ src, const int* __restrict__ dst,
                       const float* __restrict__ w, const float* __restrict__ dinv,
                       float* __restrict__ nrm, int E){
    int e = blockIdx.x*blockDim.x + threadIdx.x;
    if (e < E) nrm[e] = -dinv[src[e]] * w[e] * dinv[dst[e]];
}

// out[dst] += scale * nrm[e] * X[src]   (scatter-add over 64 features; 16 threads/edge x float4)
__global__ void k_spmv(const int* __restrict__ src, const int* __restrict__ dst,
                       const float* __restrict__ nrm, const float* __restrict__ X,
                       float* __restrict__ out, int E, float scale){
    int gid = blockIdx.x*blockDim.x + threadIdx.x;
    int e = gid >> 4;
    if (e >= E) return;
    int q = (gid & 15) << 2;
    float s = scale * nrm[e];
    const float4 v = *reinterpret_cast<const float4*>(X + (size_t)src[e]*64 + q);
    float* o = out + (size_t)dst[e]*64 + q;
    unsafeAtomicAdd(o+0, s*v.x);
    unsafeAtomicAdd(o+1, s*v.y);
    unsafeAtomicAdd(o+2, s*v.z);
    unsafeAtomicAdd(o+3, s*v.w);
}

// gates[N][256] = [x | H | Tx1 | S2-H] @ Wcat + bcat
// grid: (ceil(N/64), 4 gate-column-blocks), block 256, 4x4 microtile.
__global__ __launch_bounds__(256) void k_gemm(
        const float* __restrict__ x, const float* __restrict__ H,
        const float* __restrict__ Tx1, const float* __restrict__ S2,
        const float* __restrict__ Wcat, const float* __restrict__ bcat,
        float* __restrict__ gates, int N){
    __shared__ float As[64][68];   // As[k][m]  (transposed A tile; +4 pad)
    __shared__ float Bs[64][68];   // Bs[k][c]
    const int t  = threadIdx.x;
    const int bm = blockIdx.x * 64;
    const int g  = blockIdx.y;
    const int tm = t & 15, tn = t >> 4;
    const int lm  = t & 63;        // A-load node row
    const int lkq = t >> 6;        // A-load k-quarter
    const int bkk = t >> 2;        // B-load k row
    const int bcb = (t & 3) << 4;  // B-load col base
    float acc[4][4] = {};

    for (int kt = 0; kt < 4; ++kt){
        // ---- stage A tile (virtual concat input) ----
        const int n = bm + lm;
        const float* srcp = (kt==0) ? x : (kt==1) ? H : (kt==2) ? Tx1 : S2;
        #pragma unroll
        for (int j = 0; j < 4; ++j){
            int k = lkq*16 + j*4;
            float4 v = make_float4(0.f,0.f,0.f,0.f);
            if (n < N){
                v = *reinterpret_cast<const float4*>(srcp + (size_t)n*64 + k);
                if (kt == 3){   // Tx2 = 2*segsum(...) - H ; S2 already holds 2*segsum
                    float4 h = *reinterpret_cast<const float4*>(H + (size_t)n*64 + k);
                    v.x -= h.x; v.y -= h.y; v.z -= h.z; v.w -= h.w;
                }
            }
            As[k+0][lm] = v.x; As[k+1][lm] = v.y; As[k+2][lm] = v.z; As[k+3][lm] = v.w;
        }
        // ---- stage B tile ----
        #pragma unroll
        for (int j = 0; j < 4; ++j){
            const float4 wv = *reinterpret_cast<const float4*>(
                Wcat + (size_t)(kt*64 + bkk)*256 + g*64 + bcb + j*4);
            *reinterpret_cast<float4*>(&Bs[bkk][bcb + j*4]) = wv;
        }
        __syncthreads();
        // ---- compute ----
        #pragma unroll 8
        for (int kk = 0; kk < 64; ++kk){
            const float4 a  = *reinterpret_cast<const float4*>(&As[kk][tm*4]);
            const float4 bq = *reinterpret_cast<const float4*>(&Bs[kk][tn*4]);
            acc[0][0] += a.x*bq.x; acc[0][1] += a.x*bq.y; acc[0][2] += a.x*bq.z; acc[0][3] += a.x*bq.w;
            acc[1][0] += a.y*bq.x; acc[1][1] += a.y*bq.y; acc[1][2] += a.y*bq.z; acc[1][3] += a.y*bq.w;
            acc[2][0] += a.z*bq.x; acc[2][1] += a.z*bq.y; acc[2][2] += a.z*bq.z; acc[2][3] += a.z*bq.w;
            acc[3][0] += a.w*bq.x; acc[3][1] += a.w*bq.y; acc[3][2] += a.w*bq.z; acc[3][3] += a.w*bq.w;
        }
        __syncthreads();
    }
    // ---- epilogue ----
    const float4 bc = *reinterpret_cast<const float4*>(bcat + g*64 + tn*4);
    #pragma unroll
    for (int i = 0; i < 4; ++i){
        int row = bm + tm*4 + i;
        if (row < N){
            float4 o;
            o.x = acc[i][0] + bc.x; o.y = acc[i][1] + bc.y;
            o.z = acc[i][2] + bc.z; o.w = acc[i][3] + bc.w;
            *reinterpret_cast<float4*>(gates + (size_t)row*256 + g*64 + tn*4) = o;
        }
    }
}

__global__ void k_gate(const float* __restrict__ gates, const float* __restrict__ wc,
                       float* __restrict__ H, float* __restrict__ C,
                       float* __restrict__ out, int N, int last){
    int idx = blockIdx.x*blockDim.x + threadIdx.x;
    if (idx >= N*16) return;
    int n = idx >> 4, q = (idx & 15) << 2;
    const float* gp = gates + (size_t)n*256;
    float4 z0 = *reinterpret_cast<const float4*>(gp + q);
    float4 z1 = *reinterpret_cast<const float4*>(gp + 64 + q);
    float4 z2 = *reinterpret_cast<const float4*>(gp + 128 + q);
    float4 z3 = *reinterpret_cast<const float4*>(gp + 192 + q);
    float4 c  = *reinterpret_cast<const float4*>(C + (size_t)n*64 + q);
    float4 w0 = *reinterpret_cast<const float4*>(wc + q);
    float4 w1 = *reinterpret_cast<const float4*>(wc + 64 + q);
    float4 w2 = *reinterpret_cast<const float4*>(wc + 128 + q);
    float4 hn, cn;
    {
        float i_ = sigf(z0.x + w0.x*c.x), f_ = sigf(z1.x + w1.x*c.x), g_ = tanhfast(z2.x);
        cn.x = f_*c.x + i_*g_; float o_ = sigf(z3.x + w2.x*cn.x); hn.x = o_*tanhfast(cn.x);
    }
    {
        float i_ = sigf(z0.y + w0.y*c.y), f_ = sigf(z1.y + w1.y*c.y), g_ = tanhfast(z2.y);
        cn.y = f_*c.y + i_*g_; float o_ = sigf(z3.y + w2.y*cn.y); hn.y = o_*tanhfast(cn.y);
    }
    {
        float i_ = sigf(z0.z + w0.z*c.z), f_ = sigf(z1.z + w1.z*c.z), g_ = tanhfast(z2.z);
        cn.z = f_*c.z + i_*g_; float o_ = sigf(z3.z + w2.z*cn.z); hn.z = o_*tanhfast(cn.z);
    }
    {
        float i_ = sigf(z0.w + w0.w*c.w), f_ = sigf(z1.w + w1.w*c.w), g_ = tanhfast(z2.w);
        cn.w = f_*c.w + i_*g_; float o_ = sigf(z3.w + w2.w*cn.w); hn.w = o_*tanhfast(cn.w);
    }
    *reinterpret_cast<float4*>(C + (size_t)n*64 + q) = cn;
    *reinterpret_cast<float4*>(H + (size_t)n*64 + q) = hn;
    if (last){
        float4 r;
        r.x = fmaxf(hn.x, 0.f); r.y = fmaxf(hn.y, 0.f);
        r.z = fmaxf(hn.z, 0.f); r.w = fmaxf(hn.w, 0.f);
        *reinterpret_cast<float4*>(out + (size_t)n*64 + q) = r;
    }
}

extern "C" void kernel_launch(void* const* d_in, const int* in_sizes, int n_in,
                              void* d_out, int out_size, void* d_ws, size_t ws_size,
                              hipStream_t stream){
    const float* x_seq = (const float*)d_in[0];
    const float* w_seq = (const float*)d_in[1];
    const float* Wx    = (const float*)d_in[2];
    const float* Th    = (const float*)d_in[3];
    const float* b     = (const float*)d_in[4];
    const float* wc    = (const float*)d_in[5];
    const int*   ei    = (const int*)d_in[6];
    float* out = (float*)d_out;

    float* ws = (float*)d_ws;
    size_t off = 0;
    float* H    = ws + off; off += (size_t)NN*64;
    float* C    = ws + off; off += (size_t)NN*64;
    float* Tx1  = ws + off; off += (size_t)NN*64;
    float* S2   = ws + off; off += (size_t)NN*64;
    float* gates= ws + off; off += (size_t)NN*256;
    float* deg  = ws + off; off += NN;
    float* dinv = ws + off; off += NN;
    float* nrm  = ws + off; off += EE;
    float* Wcat = ws + off; off += 256*256;
    float* bcat = ws + off; off += 256;

    // H and C are contiguous: zero both.
    hipMemsetAsync(H, 0, (size_t)NN*64*2*sizeof(float), stream);
    k_build_w<<<256, 256, 0, stream>>>(Wx, Th, b, Wcat, bcat);

    for (int t = 0; t < T_STEPS; ++t){
        const int* src = ei + (size_t)t*2*EE;
        const int* dst = src + EE;
        const float* w = w_seq + (size_t)t*EE;
        const float* x = x_seq + (size_t)t*NN*64;

        hipMemsetAsync(deg, 0, NN*sizeof(float), stream);
        k_deg <<<(EE+255)/256, 256, 0, stream>>>(src, w, deg, EE);
        k_dinv<<<(NN+255)/256, 256, 0, stream>>>(deg, dinv, NN);
        k_norm<<<(EE+255)/256, 256, 0, stream>>>(src, dst, w, dinv, nrm, EE);

        hipMemsetAsync(Tx1, 0, (size_t)NN*64*sizeof(float), stream);
        k_spmv<<<(EE*16+255)/256, 256, 0, stream>>>(src, dst, nrm, H, Tx1, EE, 1.0f);

        hipMemsetAsync(S2, 0, (size_t)NN*64*sizeof(float), stream);
        k_spmv<<<(EE*16+255)/256, 256, 0, stream>>>(src, dst, nrm, Tx1, S2, EE, 2.0f);

        dim3 gg((NN+63)/64, 4);
        k_gemm<<<gg, 256, 0, stream>>>(x, H, Tx1, S2, Wcat, bcat, gates, NN);
        k_gate<<<(NN*16+255)/256, 256, 0, stream>>>(gates, wc, H, C, out, NN, t==T_STEPS-1);
    }
}

// Round 2
// 2858.442 us; speedup vs baseline: 4.2829x; 4.2829x over previous
//
#include <hip/hip_runtime.h>
#include <cmath>

#define T_STEPS 8
#define NN 50000
#define EE 800000

__device__ __forceinline__ float sigf(float x){ return 1.f/(1.f + __expf(-x)); }
__device__ __forceinline__ float tanhfast(float x){ return 1.f - 2.f/(1.f + __expf(2.f*x)); }

// Build fused weight matrix Wcat[256][256]: rows = [x(64) | Tx0(64) | Tx1(64) | Tx2(64)],
// cols = [gate_i | gate_f | gate_g | gate_o]. Also bcat[256].
__global__ void k_build_w(const float* __restrict__ Wx, const float* __restrict__ Th,
                          const float* __restrict__ b, float* __restrict__ Wcat,
                          float* __restrict__ bcat){
    int idx = blockIdx.x*blockDim.x + threadIdx.x;
    if (idx >= 256*256) return;
    int k = idx >> 8, c = idx & 255;
    int g = c >> 6, cc = c & 63, kb = k >> 6, kk = k & 63;
    float v;
    if (kb == 0) v = Wx[(g*64 + kk)*64 + cc];
    else         v = Th[((g*3 + (kb-1))*64 + kk)*64 + cc];
    Wcat[idx] = v;
    if (idx < 256) bcat[idx] = b[idx];
}

__global__ void k_deg(const int* __restrict__ src, const float* __restrict__ w,
                      float* __restrict__ deg, int E){
    int e = blockIdx.x*blockDim.x + threadIdx.x;
    if (e < E) unsafeAtomicAdd(&deg[src[e]], w[e]);
}

__global__ void k_dinv(const float* __restrict__ deg, float* __restrict__ dinv, int N){
    int n = blockIdx.x*blockDim.x + threadIdx.x;
    if (n < N){
        float d = deg[n];
        dinv[n] = d > 0.f ? rsqrtf(fmaxf(d, 1e-12f)) : 0.f;
    }
}

// ---------- CSR build (per timestep) ----------
__global__ void k_hist(const int* __restrict__ dst, int* __restrict__ cnt, int E){
    int e = blockIdx.x*blockDim.x + threadIdx.x;
    if (e < E) atomicAdd(&cnt[dst[e]], 1);
}

__global__ void k_scan1(const int* __restrict__ cnt, int* __restrict__ part,
                        int* __restrict__ bsum, int N){
    __shared__ int s[256];
    int i = blockIdx.x*256 + threadIdx.x;
    int v = (i < N) ? cnt[i] : 0;
    s[threadIdx.x] = v; __syncthreads();
    #pragma unroll
    for (int off = 1; off < 256; off <<= 1){
        int t = (threadIdx.x >= off) ? s[threadIdx.x - off] : 0;
        __syncthreads();
        s[threadIdx.x] += t;
        __syncthreads();
    }
    if (i < N) part[i] = s[threadIdx.x] - v;      // exclusive
    if (threadIdx.x == 255) bsum[blockIdx.x] = s[255];
}

__global__ void k_scan2(int* __restrict__ bsum, int nb){
    __shared__ int s[256];
    int i = threadIdx.x;
    int v = (i < nb) ? bsum[i] : 0;
    s[i] = v; __syncthreads();
    #pragma unroll
    for (int off = 1; off < 256; off <<= 1){
        int t = (i >= off) ? s[i - off] : 0;
        __syncthreads();
        s[i] += t;
        __syncthreads();
    }
    if (i < nb) bsum[i] = s[i] - v;               // exclusive
}

__global__ void k_scan3(const int* __restrict__ part, const int* __restrict__ bsum,
                        int* __restrict__ row_start, int* __restrict__ cursor, int N, int E){
    int i = blockIdx.x*256 + threadIdx.x;
    if (i < N){
        int v = part[i] + bsum[blockIdx.x];
        row_start[i] = v;
        cursor[i]    = v;
    }
    if (i == 0) row_start[N] = E;
}

__global__ void k_perm(const int* __restrict__ src, const int* __restrict__ dst,
                       int* __restrict__ cursor, int* __restrict__ src_csr,
                       int* __restrict__ pos, int E){
    int e = blockIdx.x*blockDim.x + threadIdx.x;
    if (e < E){
        int p = atomicAdd(&cursor[dst[e]], 1);
        src_csr[p] = src[e];
        pos[e] = p;
    }
}

// nrm straight into CSR order
__global__ void k_norm_csr(const int* __restrict__ src, const int* __restrict__ dst,
                           const float* __restrict__ w, const float* __restrict__ dinv,
                           const int* __restrict__ pos, float* __restrict__ nrm_csr, int E){
    int e = blockIdx.x*blockDim.x + threadIdx.x;
    if (e < E) nrm_csr[pos[e]] = -dinv[src[e]] * w[e] * dinv[dst[e]];
}

// ---------- gather SpMV: out[n] = scale * sum_j nrm[j] * X[src[j]] ----------
// 16 threads per node, float4 per thread.
__global__ __launch_bounds__(256) void k_spmv_g(
        const int* __restrict__ row_start, const int* __restrict__ src_csr,
        const float* __restrict__ nrm_csr, const float* __restrict__ X,
        float* __restrict__ outb, int N, float scale){
    int gid = blockIdx.x*blockDim.x + threadIdx.x;
    int n = gid >> 4;
    if (n >= N) return;
    int q = (gid & 15) << 2;
    int beg = row_start[n], end = row_start[n+1];
    float4 acc = make_float4(0.f,0.f,0.f,0.f);
    for (int j = beg; j < end; ++j){
        float s = nrm_csr[j];
        int  sn = src_csr[j];
        const float4 v = *reinterpret_cast<const float4*>(X + (size_t)sn*64 + q);
        acc.x += s*v.x; acc.y += s*v.y; acc.z += s*v.z; acc.w += s*v.w;
    }
    acc.x *= scale; acc.y *= scale; acc.z *= scale; acc.w *= scale;
    *reinterpret_cast<float4*>(outb + (size_t)n*64 + q) = acc;
}

// gates[N][256] = [x | H | Tx1 | S2-H] @ Wcat + bcat
__global__ __launch_bounds__(256) void k_gemm(
        const float* __restrict__ x, const float* __restrict__ H,
        const float* __restrict__ Tx1, const float* __restrict__ S2,
        const float* __restrict__ Wcat, const float* __restrict__ bcat,
        float* __restrict__ gates, int N){
    __shared__ float As[64][68];
    __shared__ float Bs[64][68];
    const int t  = threadIdx.x;
    const int bm = blockIdx.x * 64;
    const int g  = blockIdx.y;
    const int tm = t & 15, tn = t >> 4;
    const int lm  = t & 63;
    const int lkq = t >> 6;
    const int bkk = t >> 2;
    const int bcb = (t & 3) << 4;
    float acc[4][4] = {};

    for (int kt = 0; kt < 4; ++kt){
        const int n = bm + lm;
        const float* srcp = (kt==0) ? x : (kt==1) ? H : (kt==2) ? Tx1 : S2;
        #pragma unroll
        for (int j = 0; j < 4; ++j){
            int k = lkq*16 + j*4;
            float4 v = make_float4(0.f,0.f,0.f,0.f);
            if (n < N){
                v = *reinterpret_cast<const float4*>(srcp + (size_t)n*64 + k);
                if (kt == 3){
                    float4 h = *reinterpret_cast<const float4*>(H + (size_t)n*64 + k);
                    v.x -= h.x; v.y -= h.y; v.z -= h.z; v.w -= h.w;
                }
            }
            As[k+0][lm] = v.x; As[k+1][lm] = v.y; As[k+2][lm] = v.z; As[k+3][lm] = v.w;
        }
        #pragma unroll
        for (int j = 0; j < 4; ++j){
            const float4 wv = *reinterpret_cast<const float4*>(
                Wcat + (size_t)(kt*64 + bkk)*256 + g*64 + bcb + j*4);
            *reinterpret_cast<float4*>(&Bs[bkk][bcb + j*4]) = wv;
        }
        __syncthreads();
        #pragma unroll 8
        for (int kk = 0; kk < 64; ++kk){
            const float4 a  = *reinterpret_cast<const float4*>(&As[kk][tm*4]);
            const float4 bq = *reinterpret_cast<const float4*>(&Bs[kk][tn*4]);
            acc[0][0] += a.x*bq.x; acc[0][1] += a.x*bq.y; acc[0][2] += a.x*bq.z; acc[0][3] += a.x*bq.w;
            acc[1][0] += a.y*bq.x; acc[1][1] += a.y*bq.y; acc[1][2] += a.y*bq.z; acc[1][3] += a.y*bq.w;
            acc[2][0] += a.z*bq.x; acc[2][1] += a.z*bq.y; acc[2][2] += a.z*bq.z; acc[2][3] += a.z*bq.w;
            acc[3][0] += a.w*bq.x; acc[3][1] += a.w*bq.y; acc[3][2] += a.w*bq.z; acc[3][3] += a.w*bq.w;
        }
        __syncthreads();
    }
    const float4 bc = *reinterpret_cast<const float4*>(bcat + g*64 + tn*4);
    #pragma unroll
    for (int i = 0; i < 4; ++i){
        int row = bm + tm*4 + i;
        if (row < N){
            float4 o;
            o.x = acc[i][0] + bc.x; o.y = acc[i][1] + bc.y;
            o.z = acc[i][2] + bc.z; o.w = acc[i][3] + bc.w;
            *reinterpret_cast<float4*>(gates + (size_t)row*256 + g*64 + tn*4) = o;
        }
    }
}

__global__ void k_gate(const float* __restrict__ gates, const float* __restrict__ wc,
                       float* __restrict__ H, float* __restrict__ C,
                       float* __restrict__ out, int N, int last){
    int idx = blockIdx.x*blockDim.x + threadIdx.x;
    if (idx >= N*16) return;
    int n = idx >> 4, q = (idx & 15) << 2;
    const float* gp = gates + (size_t)n*256;
    float4 z0 = *reinterpret_cast<const float4*>(gp + q);
    float4 z1 = *reinterpret_cast<const float4*>(gp + 64 + q);
    float4 z2 = *reinterpret_cast<const float4*>(gp + 128 + q);
    float4 z3 = *reinterpret_cast<const float4*>(gp + 192 + q);
    float4 c  = *reinterpret_cast<const float4*>(C + (size_t)n*64 + q);
    float4 w0 = *reinterpret_cast<const float4*>(wc + q);
    float4 w1 = *reinterpret_cast<const float4*>(wc + 64 + q);
    float4 w2 = *reinterpret_cast<const float4*>(wc + 128 + q);
    float4 hn, cn;
    {
        float i_ = sigf(z0.x + w0.x*c.x), f_ = sigf(z1.x + w1.x*c.x), g_ = tanhfast(z2.x);
        cn.x = f_*c.x + i_*g_; float o_ = sigf(z3.x + w2.x*cn.x); hn.x = o_*tanhfast(cn.x);
    }
    {
        float i_ = sigf(z0.y + w0.y*c.y), f_ = sigf(z1.y + w1.y*c.y), g_ = tanhfast(z2.y);
        cn.y = f_*c.y + i_*g_; float o_ = sigf(z3.y + w2.y*cn.y); hn.y = o_*tanhfast(cn.y);
    }
    {
        float i_ = sigf(z0.z + w0.z*c.z), f_ = sigf(z1.z + w1.z*c.z), g_ = tanhfast(z2.z);
        cn.z = f_*c.z + i_*g_; float o_ = sigf(z3.z + w2.z*cn.z); hn.z = o_*tanhfast(cn.z);
    }
    {
        float i_ = sigf(z0.w + w0.w*c.w), f_ = sigf(z1.w + w1.w*c.w), g_ = tanhfast(z2.w);
        cn.w = f_*c.w + i_*g_; float o_ = sigf(z3.w + w2.w*cn.w); hn.w = o_*tanhfast(cn.w);
    }
    *reinterpret_cast<float4*>(C + (size_t)n*64 + q) = cn;
    *reinterpret_cast<float4*>(H + (size_t)n*64 + q) = hn;
    if (last){
        float4 r;
        r.x = fmaxf(hn.x, 0.f); r.y = fmaxf(hn.y, 0.f);
        r.z = fmaxf(hn.z, 0.f); r.w = fmaxf(hn.w, 0.f);
        *reinterpret_cast<float4*>(out + (size_t)n*64 + q) = r;
    }
}

extern "C" void kernel_launch(void* const* d_in, const int* in_sizes, int n_in,
                              void* d_out, int out_size, void* d_ws, size_t ws_size,
                              hipStream_t stream){
    const float* x_seq = (const float*)d_in[0];
    const float* w_seq = (const float*)d_in[1];
    const float* Wx    = (const float*)d_in[2];
    const float* Th    = (const float*)d_in[3];
    const float* b     = (const float*)d_in[4];
    const float* wc    = (const float*)d_in[5];
    const int*   ei    = (const int*)d_in[6];
    float* out = (float*)d_out;

    float* ws = (float*)d_ws;
    size_t off = 0;
    float* H      = ws + off; off += (size_t)NN*64;
    float* C      = ws + off; off += (size_t)NN*64;
    float* Tx1    = ws + off; off += (size_t)NN*64;
    float* S2     = ws + off; off += (size_t)NN*64;
    float* gates  = ws + off; off += (size_t)NN*256;
    float* deg    = ws + off; off += NN;
    float* dinv   = ws + off; off += NN;
    float* nrm_csr= ws + off; off += EE;
    float* Wcat   = ws + off; off += 256*256;
    float* bcat   = ws + off; off += 256;
    int* cnt      = (int*)(ws + off); off += NN;
    int* part     = (int*)(ws + off); off += NN;
    int* bsum     = (int*)(ws + off); off += 256;
    int* row_start= (int*)(ws + off); off += NN + 1;
    int* cursor   = (int*)(ws + off); off += NN;
    int* src_csr  = (int*)(ws + off); off += EE;
    int* pos      = (int*)(ws + off); off += EE;

    const int NB = (NN + 255)/256;   // 196 scan blocks

    hipMemsetAsync(H, 0, (size_t)NN*64*2*sizeof(float), stream);
    k_build_w<<<256, 256, 0, stream>>>(Wx, Th, b, Wcat, bcat);

    for (int t = 0; t < T_STEPS; ++t){
        const int* src = ei + (size_t)t*2*EE;
        const int* dst = src + EE;
        const float* w = w_seq + (size_t)t*EE;
        const float* x = x_seq + (size_t)t*NN*64;

        // degree + dinv (by src)
        hipMemsetAsync(deg, 0, NN*sizeof(float), stream);
        k_deg <<<(EE+255)/256, 256, 0, stream>>>(src, w, deg, EE);
        k_dinv<<<(NN+255)/256, 256, 0, stream>>>(deg, dinv, NN);

        // CSR by dst
        hipMemsetAsync(cnt, 0, NN*sizeof(int), stream);
        k_hist <<<(EE+255)/256, 256, 0, stream>>>(dst, cnt, EE);
        k_scan1<<<NB, 256, 0, stream>>>(cnt, part, bsum, NN);
        k_scan2<<<1, 256, 0, stream>>>(bsum, NB);
        k_scan3<<<NB, 256, 0, stream>>>(part, bsum, row_start, cursor, NN, EE);
        k_perm <<<(EE+255)/256, 256, 0, stream>>>(src, dst, cursor, src_csr, pos, EE);
        k_norm_csr<<<(EE+255)/256, 256, 0, stream>>>(src, dst, w, dinv, pos, nrm_csr, EE);

        // two dependent gather SpMVs
        k_spmv_g<<<(NN*16+255)/256, 256, 0, stream>>>(row_start, src_csr, nrm_csr, H,   Tx1, NN, 1.0f);
        k_spmv_g<<<(NN*16+255)/256, 256, 0, stream>>>(row_start, src_csr, nrm_csr, Tx1, S2,  NN, 2.0f);

        dim3 gg((NN+63)/64, 4);
        k_gemm<<<gg, 256, 0, stream>>>(x, H, Tx1, S2, Wcat, bcat, gates, NN);
        k_gate<<<(NN*16+255)/256, 256, 0, stream>>>(gates, wc, H, C, out, NN, t==T_STEPS-1);
    }
}